// Round 3
// baseline (277.685 us; speedup 1.0000x reference)
//
#include <hip/hip_runtime.h>

// Problem constants (from reference)
constexpr int kB   = 128;
constexpr int kU   = 4;
constexpr int kNBS = 64;
constexpr int kS   = 408;
constexpr int kS4  = kS / 4;                               // 102 float4 per row
constexpr unsigned kNQ = (unsigned)kB * kU * kNBS * kS4;   // 3,342,336 float4 groups
constexpr int kChunk   = 8;                                // NBS rows per thread
constexpr unsigned kThreads = kNQ / kChunk;                // 417,792 threads
constexpr float kEmW     = 0.01f;
constexpr float kInvNRad = 1.0f / ((float)kB * kU * kNBS * kS);
constexpr float kInvNAtt = 1.0f / ((float)kB * kU * kS);

// Native clang vector type — required by __builtin_nontemporal_load.
typedef float vfloat4 __attribute__((ext_vector_type(4)));

// R11 == R10 resubmitted (previous run died to a container-acquisition
// infra failure, not a kernel problem).
//
// R10: R8 (NT loads, chunk=8, single 32-load batch) with the occupancy cap
// lifted: __launch_bounds__(256,6) instead of (256,3).
//
// R9 post-mortem: removing NT made it 1.8x SLOWER with unchanged FETCH_SIZE
// -> the nt evict-first policy protects L1/L2 from the 214 MB stream; keep it.
//
// R8 counters showed VGPR_Count=84 even with a 168-VGPR budget -> the
// compiler naturally fits 6-waves/SIMD occupancy (budget 512/6 = 85).
// The (256,3) cap was therefore pure loss: 12-wave/CU ceiling, 2.1 block
// generations (1632 blocks / 3-per-CU), 21% measured occupancy. At 6
// blocks/CU the grid is ~one generation (6.375 blocks/CU) and wave-level
// memory parallelism doubles. Watch: VGPR_Count must stay <=85 and
// WRITE_SIZE must stay ~51 KB (MB-range WRITE_SIZE = scratch spill -> revert).
//
// Mapping: tid in [0, 417792).
//   s4    = tid % 102                  (fastest dim -> coalesced)
//   rem   = tid / 102   in [0, 4096)
//   chunk = rem % 8, bu = rem / 8      (bu in [0,512) = b*U+u)
//   rows r = bu*64 + chunk*8 + j, j=0..7; streaming q_j = r*102 + s4
//   atten a = bu*102 + s4 — loaded once, reused for all 8 rows.
__global__ void __launch_bounds__(256, 6)
prism_loss_kernel(const vfloat4* __restrict__ atten_re,
                  const vfloat4* __restrict__ atten_im,
                  const vfloat4* __restrict__ rad_re,
                  const vfloat4* __restrict__ rad_im,
                  const vfloat4* __restrict__ tgt_re,
                  const vfloat4* __restrict__ tgt_im,
                  const vfloat4* __restrict__ weights,
                  float* __restrict__ out)
{
    const unsigned tid   = blockIdx.x * 256 + threadIdx.x;  // grid sized exactly
    const unsigned rem   = tid / 102u;                      // magic-mul div
    const unsigned s4    = tid - rem * 102u;
    const unsigned chunk = rem & 7u;
    const unsigned bu    = rem >> 3;
    const unsigned qbase = (bu * 64u + chunk * 8u) * 102u + s4;
    const unsigned abase = bu * 102u + s4;
    const bool do_att = (chunk == 0u);

    const vfloat4 w  = weights[s4];
    const vfloat4 ar = atten_re[abase];
    const vfloat4 ai = atten_im[abase];

    // Single batch: all 32 NT loads issued before any use; the register
    // allocator schedules them into what fits the VGPR budget.
    vfloat4 rr[8], ri[8], tr[8], ti[8];
    #pragma unroll
    for (int j = 0; j < 8; ++j) {
        const unsigned q = qbase + (unsigned)j * 102u;
        rr[j] = __builtin_nontemporal_load(&rad_re[q]);
        ri[j] = __builtin_nontemporal_load(&rad_im[q]);
        tr[j] = __builtin_nontemporal_load(&tgt_re[q]);
        ti[j] = __builtin_nontemporal_load(&tgt_im[q]);
    }

    float recv   = 0.0f;
    float em_rad = 0.0f;
    float em_att = 0.0f;

    // Consume in issue order -> compiler emits incremental vmcnt(N) waits.
    #pragma unroll
    for (int j = 0; j < 8; ++j) {
        #pragma unroll
        for (int c = 0; c < 4; ++c) {
            const float a_r = ar[c], a_i = ai[c];
            const float r_r = rr[j][c], r_i = ri[j][c];
            const float pr = a_r * r_r - a_i * r_i;
            const float pi = a_r * r_i + a_i * r_r;
            const float dr = pr - tr[j][c];
            const float di = pi - ti[j][c];
            recv = fmaf((dr * dr + di * di), w[c], recv);
            float rm = sqrtf(fmaf(r_r, r_r, r_i * r_i)) - 10.0f;
            rm = fmaxf(rm, 0.0f);
            em_rad = fmaf(rm, rm, em_rad);
        }
    }

    if (do_att) {
        #pragma unroll
        for (int c = 0; c < 4; ++c) {
            float am = sqrtf(fmaf(ar[c], ar[c], ai[c] * ai[c])) - 1.0f;
            am = fmaxf(am, 0.0f);
            em_att = fmaf(am, am, em_att);
        }
    }

    float acc = recv + kEmW * (em_rad * kInvNRad + em_att * kInvNAtt);

    // Wave-64 reduction.
    #pragma unroll
    for (int off = 32; off > 0; off >>= 1)
        acc += __shfl_down(acc, off, 64);

    __shared__ float sdata[4];
    const int lane = threadIdx.x & 63;
    const int wave = threadIdx.x >> 6;
    if (lane == 0) sdata[wave] = acc;
    __syncthreads();
    if (threadIdx.x == 0) {
        atomicAdd(out, sdata[0] + sdata[1] + sdata[2] + sdata[3]);
    }
}

extern "C" void kernel_launch(void* const* d_in, const int* in_sizes, int n_in,
                              void* d_out, int out_size, void* d_ws, size_t ws_size,
                              hipStream_t stream) {
    const vfloat4* atten_re = (const vfloat4*)d_in[0];
    const vfloat4* atten_im = (const vfloat4*)d_in[1];
    const vfloat4* rad_re   = (const vfloat4*)d_in[2];
    const vfloat4* rad_im   = (const vfloat4*)d_in[3];
    const vfloat4* tgt_re   = (const vfloat4*)d_in[4];
    const vfloat4* tgt_im   = (const vfloat4*)d_in[5];
    const vfloat4* weights  = (const vfloat4*)d_in[6];
    float* out = (float*)d_out;

    // d_out is re-poisoned to 0xAA before every timed launch; zero it.
    (void)hipMemsetAsync(out, 0, sizeof(float), stream);

    // 1632 blocks * 256 threads == kThreads exactly (no bounds checks needed).
    prism_loss_kernel<<<(int)(kThreads / 256), 256, 0, stream>>>(
        atten_re, atten_im, rad_re, rad_im, tgt_re, tgt_im, weights, out);
}

// Round 4
// 209.109 us; speedup vs baseline: 1.3279x; 1.3279x over previous
//
#include <hip/hip_runtime.h>

// Problem constants (from reference)
constexpr int kB   = 128;
constexpr int kU   = 4;
constexpr int kNBS = 64;
constexpr int kS   = 408;
constexpr int kS4  = kS / 4;                               // 102 float4 per row
constexpr unsigned kNQ = (unsigned)kB * kU * kNBS * kS4;   // 3,342,336 float4 groups
constexpr int kChunk   = 8;                                // NBS rows per thread
constexpr unsigned kThreads = kNQ / kChunk;                // 417,792 threads
constexpr float kEmW     = 0.01f;
constexpr float kInvNRad = 1.0f / ((float)kB * kU * kNBS * kS);
constexpr float kInvNAtt = 1.0f / ((float)kB * kU * kS);

// Native clang vector type — required by __builtin_nontemporal_load.
typedef float vfloat4 __attribute__((ext_vector_type(4)));

// R12 == R8 restored verbatim (champion config, 44.5-44.9 us).
//
// Session ledger:
//  R8  (256,3), NT, 32-load batch:  44.9 us, VGPR=84, WRITE=51KB  <- champion
//  R9  plain loads (no NT):         79.5 us — L2 thrash, FETCH unchanged
//      -> nt evict-first policy protects L1/L2 from the 214 MB stream. KEEP.
//  R11 (256,6):                    126.0 us, WRITE=162MB — spill tripwire
//      -> 85-VGPR budget can't hold the 32-load batch; allocator spills
//         ~128 VGPRs of load data to scratch. Also proves occupancy is not
//         the lever (50% measured, 3x slower).
//
// Standing theory: the ~4.8 TB/s aggregate service rate (2.67 TB/s HBM
// + ~2.2 TB/s LLC, FETCH ~117 of 215.6 MB logical) is a shared-path
// ceiling (MALL/fabric) for this streaming pattern — insensitive to
// per-wave MLP (8->16 loads +23%, 16->32 neutral), occupancy (R11), and
// L2 policy (R9 FETCH unchanged). Naive HBM-only roofline would be
// ~34 us; LLC hits put the achieved floor near 44.5 us.
//
// Mapping: tid in [0, 417792).
//   s4    = tid % 102                  (fastest dim -> coalesced)
//   rem   = tid / 102   in [0, 4096)
//   chunk = rem % 8, bu = rem / 8      (bu in [0,512) = b*U+u)
//   rows r = bu*64 + chunk*8 + j, j=0..7; streaming q_j = r*102 + s4
//   atten a = bu*102 + s4 — loaded once, reused for all 8 rows.
__global__ void __launch_bounds__(256, 3)
prism_loss_kernel(const vfloat4* __restrict__ atten_re,
                  const vfloat4* __restrict__ atten_im,
                  const vfloat4* __restrict__ rad_re,
                  const vfloat4* __restrict__ rad_im,
                  const vfloat4* __restrict__ tgt_re,
                  const vfloat4* __restrict__ tgt_im,
                  const vfloat4* __restrict__ weights,
                  float* __restrict__ out)
{
    const unsigned tid   = blockIdx.x * 256 + threadIdx.x;  // grid sized exactly
    const unsigned rem   = tid / 102u;                      // magic-mul div
    const unsigned s4    = tid - rem * 102u;
    const unsigned chunk = rem & 7u;
    const unsigned bu    = rem >> 3;
    const unsigned qbase = (bu * 64u + chunk * 8u) * 102u + s4;
    const unsigned abase = bu * 102u + s4;
    const bool do_att = (chunk == 0u);

    const vfloat4 w  = weights[s4];
    const vfloat4 ar = atten_re[abase];
    const vfloat4 ai = atten_im[abase];

    // Single batch: all 32 NT loads issued before any use. With the
    // 168-VGPR budget from (256,3) the allocator keeps ~16-20 truly in
    // flight and staggers the rest — measured best config.
    vfloat4 rr[8], ri[8], tr[8], ti[8];
    #pragma unroll
    for (int j = 0; j < 8; ++j) {
        const unsigned q = qbase + (unsigned)j * 102u;
        rr[j] = __builtin_nontemporal_load(&rad_re[q]);
        ri[j] = __builtin_nontemporal_load(&rad_im[q]);
        tr[j] = __builtin_nontemporal_load(&tgt_re[q]);
        ti[j] = __builtin_nontemporal_load(&tgt_im[q]);
    }

    float recv   = 0.0f;
    float em_rad = 0.0f;
    float em_att = 0.0f;

    // Consume in issue order -> compiler emits incremental vmcnt(N) waits.
    #pragma unroll
    for (int j = 0; j < 8; ++j) {
        #pragma unroll
        for (int c = 0; c < 4; ++c) {
            const float a_r = ar[c], a_i = ai[c];
            const float r_r = rr[j][c], r_i = ri[j][c];
            const float pr = a_r * r_r - a_i * r_i;
            const float pi = a_r * r_i + a_i * r_r;
            const float dr = pr - tr[j][c];
            const float di = pi - ti[j][c];
            recv = fmaf((dr * dr + di * di), w[c], recv);
            float rm = sqrtf(fmaf(r_r, r_r, r_i * r_i)) - 10.0f;
            rm = fmaxf(rm, 0.0f);
            em_rad = fmaf(rm, rm, em_rad);
        }
    }

    if (do_att) {
        #pragma unroll
        for (int c = 0; c < 4; ++c) {
            float am = sqrtf(fmaf(ar[c], ar[c], ai[c] * ai[c])) - 1.0f;
            am = fmaxf(am, 0.0f);
            em_att = fmaf(am, am, em_att);
        }
    }

    float acc = recv + kEmW * (em_rad * kInvNRad + em_att * kInvNAtt);

    // Wave-64 reduction.
    #pragma unroll
    for (int off = 32; off > 0; off >>= 1)
        acc += __shfl_down(acc, off, 64);

    __shared__ float sdata[4];
    const int lane = threadIdx.x & 63;
    const int wave = threadIdx.x >> 6;
    if (lane == 0) sdata[wave] = acc;
    __syncthreads();
    if (threadIdx.x == 0) {
        atomicAdd(out, sdata[0] + sdata[1] + sdata[2] + sdata[3]);
    }
}

extern "C" void kernel_launch(void* const* d_in, const int* in_sizes, int n_in,
                              void* d_out, int out_size, void* d_ws, size_t ws_size,
                              hipStream_t stream) {
    const vfloat4* atten_re = (const vfloat4*)d_in[0];
    const vfloat4* atten_im = (const vfloat4*)d_in[1];
    const vfloat4* rad_re   = (const vfloat4*)d_in[2];
    const vfloat4* rad_im   = (const vfloat4*)d_in[3];
    const vfloat4* tgt_re   = (const vfloat4*)d_in[4];
    const vfloat4* tgt_im   = (const vfloat4*)d_in[5];
    const vfloat4* weights  = (const vfloat4*)d_in[6];
    float* out = (float*)d_out;

    // d_out is re-poisoned to 0xAA before every timed launch; zero it.
    (void)hipMemsetAsync(out, 0, sizeof(float), stream);

    // 1632 blocks * 256 threads == kThreads exactly (no bounds checks needed).
    prism_loss_kernel<<<(int)(kThreads / 256), 256, 0, stream>>>(
        atten_re, atten_im, rad_re, rad_im, tgt_re, tgt_im, weights, out);
}